// Round 2
// baseline (690.727 us; speedup 1.0000x reference)
//
#include <hip/hip_runtime.h>

#define N_NODES 100000
#define N_EDGES 1600000
#define DFEAT   128
#define NGRAPH  64
#define EPSV    1e-5f
#define SCAN_BLOCKS ((N_NODES + 255) / 256)   // 391
#define DEG_SCALE 268435456.0f                 // 2^28
#define DEG_MASK  ((1ULL << 42) - 1)

typedef float v4f  __attribute__((ext_vector_type(4)));
typedef short v8s  __attribute__((ext_vector_type(8)));   // 8 bf16 in 4 VGPRs
typedef unsigned short us4 __attribute__((ext_vector_type(4)));
typedef unsigned short us8 __attribute__((ext_vector_type(8)));

static __device__ __forceinline__ unsigned short f2bf(float f) {
    union { float f; unsigned int u; } v; v.f = f;
    unsigned int u = v.u;
    return (unsigned short)((u + 0x7FFFu + ((u >> 16) & 1u)) >> 16);   // RTNE
}
static __device__ __forceinline__ float bf2f(unsigned short b) {
    union { unsigned int u; float f; } v; v.u = ((unsigned int)b) << 16;
    return v.f;
}

// ---------------------------------------------------------------------------
// init: degcnt=0 (packed), fillc=0, stats/pool buffers = 0
// ---------------------------------------------------------------------------
__global__ void init_kernel(unsigned long long* __restrict__ degcnt,
                            int* __restrict__ fillc, float* __restrict__ stats0,
                            float* __restrict__ stats1, float* __restrict__ gsum,
                            float* __restrict__ gcntf) {
    int i = blockIdx.x * 256 + threadIdx.x;
    if (i < N_NODES) { degcnt[i] = 0ULL; fillc[i] = 0; }
    if (i < 256)  { stats0[i] = 0.f; stats1[i] = 0.f; }
    if (i < NGRAPH * DFEAT) gsum[i] = 0.f;
    if (i < NGRAPH) gcntf[i] = 0.f;
}

// ---------------------------------------------------------------------------
// weight prep: Wt[n][k] = bf16(W[k][n]) for 4 weights (blockIdx>>6 selects)
// ---------------------------------------------------------------------------
__global__ __launch_bounds__(256) void wprep_kernel(
    const float* __restrict__ W0, const float* __restrict__ W1,
    const float* __restrict__ W2, const float* __restrict__ W3,
    unsigned short* __restrict__ T0, unsigned short* __restrict__ T1,
    unsigned short* __restrict__ T2, unsigned short* __restrict__ T3) {
    int which = blockIdx.x >> 6;
    int i = (blockIdx.x & 63) * 256 + threadIdx.x;   // 0..16383
    const float* W = which == 0 ? W0 : which == 1 ? W1 : which == 2 ? W2 : W3;
    unsigned short* T = which == 0 ? T0 : which == 1 ? T1 : which == 2 ? T2 : T3;
    int n = i >> 7, k = i & 127;
    T[n * 128 + k] = f2bf(W[k * 128 + n]);
}

// ---------------------------------------------------------------------------
// ONE packed u64 atomic per edge: cnt in [42:63], fixed-point sum(w) in [0:41]
// ---------------------------------------------------------------------------
__global__ void edge_degcnt_kernel(const int* __restrict__ ei, const float* __restrict__ ea,
                                   unsigned long long* __restrict__ degcnt) {
    int e = blockIdx.x * 256 + threadIdx.x;
    if (e >= N_EDGES) return;
    int d = ei[N_EDGES + e];
    float w = ea[2 * e + 1];           // w in [0,1)
    unsigned long long v = (1ULL << 42) | (unsigned long long)(w * DEG_SCALE);
    atomicAdd(&degcnt[d], v);
}

// unpack: cnt[i] (for scan) and dinv[i] = rsqrt(1 + sum_w)
__global__ void dinv_kernel(const unsigned long long* __restrict__ degcnt,
                            int* __restrict__ cnt, float* __restrict__ dinv) {
    int i = blockIdx.x * 256 + threadIdx.x;
    if (i >= N_NODES) return;
    unsigned long long u = degcnt[i];
    cnt[i] = (int)(u >> 42);
    float deg = 1.0f + (float)(u & DEG_MASK) * (1.0f / DEG_SCALE);
    dinv[i] = rsqrtf(deg);
}

// ---------------------------------------------------------------------------
// 3-phase device-wide exclusive scan of cnt -> rowptr
// ---------------------------------------------------------------------------
__global__ __launch_bounds__(256) void scan1_kernel(const int* __restrict__ cnt,
                                                    int* __restrict__ blockSum) {
    __shared__ int lds[256];
    int i = blockIdx.x * 256 + threadIdx.x;
    int t = threadIdx.x;
    lds[t] = (i < N_NODES) ? cnt[i] : 0;
    __syncthreads();
    for (int off = 128; off > 0; off >>= 1) {
        if (t < off) lds[t] += lds[t + off];
        __syncthreads();
    }
    if (t == 0) blockSum[blockIdx.x] = lds[0];
}

__global__ __launch_bounds__(512) void scan2_kernel(int* __restrict__ blockSum) {
    __shared__ int lds[512];
    int t = threadIdx.x;
    int v = (t < SCAN_BLOCKS) ? blockSum[t] : 0;
    lds[t] = v;
    __syncthreads();
    for (int off = 1; off < 512; off <<= 1) {
        int u = (t >= off) ? lds[t - off] : 0;
        __syncthreads();
        lds[t] += u;
        __syncthreads();
    }
    if (t < SCAN_BLOCKS) blockSum[t] = lds[t] - v;  // exclusive
}

__global__ __launch_bounds__(256) void scan3_kernel(const int* __restrict__ cnt,
                                                    const int* __restrict__ blockSum,
                                                    int* __restrict__ rowptr) {
    __shared__ int lds[256];
    int i = blockIdx.x * 256 + threadIdx.x;
    int t = threadIdx.x;
    int v = (i < N_NODES) ? cnt[i] : 0;
    lds[t] = v;
    __syncthreads();
    for (int off = 1; off < 256; off <<= 1) {
        int u = (t >= off) ? lds[t - off] : 0;
        __syncthreads();
        lds[t] += u;
        __syncthreads();
    }
    if (i < N_NODES) rowptr[i] = blockSum[blockIdx.x] + lds[t] - v;
    if (i == 0) rowptr[N_NODES] = N_EDGES;
}

// ---------------------------------------------------------------------------
// fill CSR: edges[pos] = {src, bitcast(val)} in ONE 8B store
// ---------------------------------------------------------------------------
__global__ void fill_kernel(const int* __restrict__ ei, const float* __restrict__ ea,
                            const float* __restrict__ dinv, const int* __restrict__ rowptr,
                            int* __restrict__ fillc, int2* __restrict__ edges) {
    int e = blockIdx.x * 256 + threadIdx.x;
    if (e >= N_EDGES) return;
    int s = ei[e], d = ei[N_EDGES + e];
    float w = ea[2 * e + 1];
    float nrm = dinv[s] * w * dinv[d];
    int pos = rowptr[d] + atomicAdd(&fillc[d], 1);
    edges[pos] = make_int2(s, __float_as_int(nrm));
}

// ---------------------------------------------------------------------------
// MFMA bf16 GEMM: Out[n x 128] = f(X) @ Wt^T (+bias)(+relu)
// ---------------------------------------------------------------------------
__global__ __launch_bounds__(256) void gemm_bf16_kernel(
    const void* __restrict__ Xv, int x_is_f32,
    const unsigned short* __restrict__ Wt,
    void* __restrict__ Outv, int out_is_f32,
    const float* __restrict__ bnp, const float* __restrict__ bias, int do_relu) {
    __shared__ unsigned short Xs[128][136];
    __shared__ unsigned short Ws[128][136];
    const int tid = threadIdx.x;
    const int rb = blockIdx.x * 128;

#pragma unroll
    for (int it = 0; it < 8; ++it) {
        int flat = it * 2048 + tid * 8;
        int n = flat >> 7, k = flat & 127;
        *(us8*)&Ws[n][k] = *(const us8*)&Wt[n * 128 + k];
    }
    if (x_is_f32) {
        const float* X = (const float*)Xv;
#pragma unroll
        for (int it = 0; it < 16; ++it) {
            int flat = it * 1024 + tid * 4;
            int r = flat >> 7, k = flat & 127;
            float4 v = make_float4(0.f, 0.f, 0.f, 0.f);
            if (rb + r < N_NODES) v = *(const float4*)&X[(size_t)(rb + r) * 128 + k];
            if (bnp) {
                v.x = v.x * bnp[k]     + bnp[128 + k];
                v.y = v.y * bnp[k + 1] + bnp[129 + k];
                v.z = v.z * bnp[k + 2] + bnp[130 + k];
                v.w = v.w * bnp[k + 3] + bnp[131 + k];
            }
            us4 o; o.x = f2bf(v.x); o.y = f2bf(v.y); o.z = f2bf(v.z); o.w = f2bf(v.w);
            *(us4*)&Xs[r][k] = o;
        }
    } else {
        const unsigned short* X = (const unsigned short*)Xv;
#pragma unroll
        for (int it = 0; it < 8; ++it) {
            int flat = it * 2048 + tid * 8;
            int r = flat >> 7, k = flat & 127;
            us8 v = {0, 0, 0, 0, 0, 0, 0, 0};
            if (rb + r < N_NODES) v = *(const us8*)&X[(size_t)(rb + r) * 128 + k];
            if (bnp) {
#pragma unroll
                for (int j = 0; j < 8; ++j)
                    v[j] = f2bf(bf2f(v[j]) * bnp[k + j] + bnp[128 + k + j]);
            }
            *(us8*)&Xs[r][k] = v;
        }
    }
    __syncthreads();

    const int wv = tid >> 6, lane = tid & 63;
    const int q = lane >> 4, c16 = lane & 15;
    v4f acc[2][8];
#pragma unroll
    for (int i = 0; i < 2; ++i)
#pragma unroll
        for (int j = 0; j < 8; ++j) acc[i][j] = (v4f){0.f, 0.f, 0.f, 0.f};

#pragma unroll
    for (int ks = 0; ks < 4; ++ks) {
        v8s a0 = *(const v8s*)&Xs[wv * 32 + c16][ks * 32 + q * 8];
        v8s a1 = *(const v8s*)&Xs[wv * 32 + 16 + c16][ks * 32 + q * 8];
#pragma unroll
        for (int nt = 0; nt < 8; ++nt) {
            v8s b = *(const v8s*)&Ws[nt * 16 + c16][ks * 32 + q * 8];
            acc[0][nt] = __builtin_amdgcn_mfma_f32_16x16x32_bf16(a0, b, acc[0][nt], 0, 0, 0);
            acc[1][nt] = __builtin_amdgcn_mfma_f32_16x16x32_bf16(a1, b, acc[1][nt], 0, 0, 0);
        }
    }

#pragma unroll
    for (int mt = 0; mt < 2; ++mt) {
#pragma unroll
        for (int nt = 0; nt < 8; ++nt) {
            int col = nt * 16 + c16;
            float bcol = bias ? bias[col] : 0.f;
#pragma unroll
            for (int r = 0; r < 4; ++r) {
                int row = rb + wv * 32 + mt * 16 + q * 4 + r;
                if (row >= N_NODES) continue;
                float o = acc[mt][nt][r] + bcol;
                if (do_relu) o = fmaxf(o, 0.f);
                if (out_is_f32) ((float*)Outv)[(size_t)row * 128 + col] = o;
                else ((unsigned short*)Outv)[(size_t)row * 128 + col] = f2bf(o);
            }
        }
    }
}

// ---------------------------------------------------------------------------
// aggregation (bf16 gather) + self term + bias + relu + BN stats (fp32)
// 1 wave/row, lane owns features {2*lane, 2*lane+1}; edges as int2{src,val}
// R2: edge records for a whole 64-edge chunk are fetched in ONE coalesced
// per-lane load; indices/weights extracted via v_readlane (register-only).
// Gathers then issue back-to-back with no uniform-load latency in between.
// Tail lanes clamp index to the last edge (L1-hit) with weight forced to 0.
// ---------------------------------------------------------------------------
__global__ __launch_bounds__(256) void agg_relu_bf16_kernel(
    const unsigned short* __restrict__ H, const int* __restrict__ rowptr,
    const int2* __restrict__ edges,
    const float* __restrict__ dinv, const float* __restrict__ bias,
    unsigned short* __restrict__ outb, float* __restrict__ stats, int nwaves) {
    __shared__ float red[1024];
    const int tid = threadIdx.x;
    const int wv = tid >> 6;
    const int lane = tid & 63;
    const float bx = bias[2 * lane], by = bias[2 * lane + 1];
    const unsigned int* __restrict__ H4 = (const unsigned int*)H;   // 64 uints/row
    unsigned int* __restrict__ O4 = (unsigned int*)outb;
    float s0 = 0.f, q0 = 0.f, s1 = 0.f, q1 = 0.f;

    for (int i = blockIdx.x * 4 + wv; i < N_NODES; i += nwaves) {
        int beg = __builtin_amdgcn_readfirstlane(rowptr[i]);
        int end = __builtin_amdgcn_readfirstlane(rowptr[i + 1]);
        // hoisted: self row + dinv in flight during the whole edge loop
        float di = dinv[i];
        unsigned int hs = H4[(size_t)i * 64 + lane];
        float px0 = 0.f, py0 = 0.f, px1 = 0.f, py1 = 0.f;
        float px2 = 0.f, py2 = 0.f, px3 = 0.f, py3 = 0.f;

        for (int c = beg; c < end; c += 64) {
            int n = end - c;
            if (n > 64) n = 64;
            // one coalesced load: 64 edge records into lane registers
            int idx = c + lane;
            if (idx >= end) idx = end - 1;
            int2 ev = edges[idx];
            if (c + lane >= end) ev.y = 0;   // zero weight for tail slots

            for (int k = 0; k < n; k += 8) {
                int   i0 = __builtin_amdgcn_readlane(ev.x, k + 0);
                int   i1 = __builtin_amdgcn_readlane(ev.x, k + 1);
                int   i2 = __builtin_amdgcn_readlane(ev.x, k + 2);
                int   i3 = __builtin_amdgcn_readlane(ev.x, k + 3);
                int   i4 = __builtin_amdgcn_readlane(ev.x, k + 4);
                int   i5 = __builtin_amdgcn_readlane(ev.x, k + 5);
                int   i6 = __builtin_amdgcn_readlane(ev.x, k + 6);
                int   i7 = __builtin_amdgcn_readlane(ev.x, k + 7);
                float w0 = __int_as_float(__builtin_amdgcn_readlane(ev.y, k + 0));
                float w1 = __int_as_float(__builtin_amdgcn_readlane(ev.y, k + 1));
                float w2 = __int_as_float(__builtin_amdgcn_readlane(ev.y, k + 2));
                float w3 = __int_as_float(__builtin_amdgcn_readlane(ev.y, k + 3));
                float w4 = __int_as_float(__builtin_amdgcn_readlane(ev.y, k + 4));
                float w5 = __int_as_float(__builtin_amdgcn_readlane(ev.y, k + 5));
                float w6 = __int_as_float(__builtin_amdgcn_readlane(ev.y, k + 6));
                float w7 = __int_as_float(__builtin_amdgcn_readlane(ev.y, k + 7));
                unsigned int h0 = H4[(size_t)(unsigned)i0 * 64 + lane];
                unsigned int h1 = H4[(size_t)(unsigned)i1 * 64 + lane];
                unsigned int h2 = H4[(size_t)(unsigned)i2 * 64 + lane];
                unsigned int h3 = H4[(size_t)(unsigned)i3 * 64 + lane];
                unsigned int h4 = H4[(size_t)(unsigned)i4 * 64 + lane];
                unsigned int h5 = H4[(size_t)(unsigned)i5 * 64 + lane];
                unsigned int h6 = H4[(size_t)(unsigned)i6 * 64 + lane];
                unsigned int h7 = H4[(size_t)(unsigned)i7 * 64 + lane];
                px0 = fmaf(w0, bf2f((unsigned short)h0), px0);
                py0 = fmaf(w0, bf2f((unsigned short)(h0 >> 16)), py0);
                px1 = fmaf(w1, bf2f((unsigned short)h1), px1);
                py1 = fmaf(w1, bf2f((unsigned short)(h1 >> 16)), py1);
                px2 = fmaf(w2, bf2f((unsigned short)h2), px2);
                py2 = fmaf(w2, bf2f((unsigned short)(h2 >> 16)), py2);
                px3 = fmaf(w3, bf2f((unsigned short)h3), px3);
                py3 = fmaf(w3, bf2f((unsigned short)(h3 >> 16)), py3);
                px0 = fmaf(w4, bf2f((unsigned short)h4), px0);
                py0 = fmaf(w4, bf2f((unsigned short)(h4 >> 16)), py0);
                px1 = fmaf(w5, bf2f((unsigned short)h5), px1);
                py1 = fmaf(w5, bf2f((unsigned short)(h5 >> 16)), py1);
                px2 = fmaf(w6, bf2f((unsigned short)h6), px2);
                py2 = fmaf(w6, bf2f((unsigned short)(h6 >> 16)), py2);
                px3 = fmaf(w7, bf2f((unsigned short)h7), px3);
                py3 = fmaf(w7, bf2f((unsigned short)(h7 >> 16)), py3);
            }
        }
        float dd = di * di;
        float ax = (px0 + px1) + (px2 + px3);
        float ay = (py0 + py1) + (py2 + py3);
        ax = fmaf(dd, bf2f((unsigned short)hs), ax) + bx;
        ay = fmaf(dd, bf2f((unsigned short)(hs >> 16)), ay) + by;
        ax = fmaxf(ax, 0.f);
        ay = fmaxf(ay, 0.f);
        O4[(size_t)i * 64 + lane] =
            (unsigned int)f2bf(ax) | ((unsigned int)f2bf(ay) << 16);
        s0 += ax; q0 += ax * ax; s1 += ay; q1 += ay * ay;
    }

    red[wv * 128 + 2 * lane]           = s0;
    red[wv * 128 + 2 * lane + 1]       = s1;
    red[512 + wv * 128 + 2 * lane]     = q0;
    red[512 + wv * 128 + 2 * lane + 1] = q1;
    __syncthreads();
    if (tid < 128) {
        float ts = red[tid] + red[128 + tid] + red[256 + tid] + red[384 + tid];
        float tq = red[512 + tid] + red[640 + tid] + red[768 + tid] + red[896 + tid];
        atomicAdd(&stats[tid], ts);
        atomicAdd(&stats[128 + tid], tq);
    }
}

// stats -> per-feature scale/shift
__global__ void bn_finalize_kernel(const float* __restrict__ stats,
                                   const float* __restrict__ gamma,
                                   const float* __restrict__ beta,
                                   float* __restrict__ bnp) {
    int f = threadIdx.x;
    float mean = stats[f] / (float)N_NODES;
    float var = stats[128 + f] / (float)N_NODES - mean * mean;
    float sc = gamma[f] * rsqrtf(var + EPSV);
    bnp[f] = sc;
    bnp[128 + f] = beta[f] - mean * sc;
}

// ---------------------------------------------------------------------------
// pooling: batch sorted; 128 rows/block, 256 threads = (feature, row-parity),
// run-length accumulate per thread, flush on graph change. ~12 waves/CU.
// ---------------------------------------------------------------------------
__global__ __launch_bounds__(256) void pool_kernel(const float* __restrict__ h,
                                                   const int* __restrict__ batch,
                                                   float* __restrict__ gsum,
                                                   float* __restrict__ gcntf) {
    const int f = threadIdx.x & 127;
    const int half = threadIdx.x >> 7;          // 0/1: even/odd rows
    const int base = blockIdx.x * 128;
    int r = base + half;
    const int end = (base + 128 < N_NODES) ? base + 128 : N_NODES;
    if (r >= end) return;
    int cur = batch[r];
    float sum = 0.f, cnt = 0.f;
    for (; r < end; r += 2) {
        int g = batch[r];
        if (g != cur) {
            atomicAdd(&gsum[cur * 128 + f], sum);
            if (f == 0) atomicAdd(&gcntf[cur], cnt);
            sum = 0.f; cnt = 0.f; cur = g;
        }
        sum += h[(size_t)r * 128 + f];
        cnt += 1.f;
    }
    atomicAdd(&gsum[cur * 128 + f], sum);
    if (f == 0) atomicAdd(&gcntf[cur], cnt);
}

__global__ void reps_kernel(const float* __restrict__ gsum,
                            const float* __restrict__ gcntf,
                            float* __restrict__ out_reps) {
    int i = blockIdx.x * 256 + threadIdx.x;
    if (i < NGRAPH * 128) {
        int g = i >> 7;
        out_reps[i] = gsum[i] / fmaxf(gcntf[g], 1.0f);
    }
}

__global__ __launch_bounds__(128) void logits_kernel(
    const float* __restrict__ reps, const float* __restrict__ Wc1,
    const float* __restrict__ bc1, const float* __restrict__ Wc2,
    const float* __restrict__ bc2, float* __restrict__ out_logits) {
    __shared__ float repS[128];
    __shared__ float tmp[128];
    int g = blockIdx.x, t = threadIdx.x;
    repS[t] = reps[(size_t)g * 128 + t];
    __syncthreads();
    float acc = bc1[t];
    for (int k = 0; k < 128; ++k) acc = fmaf(repS[k], Wc1[k * 128 + t], acc);
    tmp[t] = fmaxf(acc, 0.f);
    __syncthreads();
    if (t < 2) {
        float a = bc2[t];
        for (int k = 0; k < 128; ++k) a = fmaf(tmp[k], Wc2[k * 2 + t], a);
        out_logits[g * 2 + t] = a;
    }
}

// ---------------------------------------------------------------------------
extern "C" void kernel_launch(void* const* d_in, const int* in_sizes, int n_in,
                              void* d_out, int out_size, void* d_ws, size_t ws_size,
                              hipStream_t stream) {
    const float* x      = (const float*)d_in[0];
    const int*   ei     = (const int*)d_in[1];
    const float* ea     = (const float*)d_in[2];
    const int*   batch  = (const int*)d_in[3];
    const float* Wg0    = (const float*)d_in[4];
    const float* bg0    = (const float*)d_in[5];
    const float* gamma0 = (const float*)d_in[6];
    const float* beta0  = (const float*)d_in[7];
    const float* Wg1    = (const float*)d_in[8];
    const float* bg1    = (const float*)d_in[9];
    const float* gamma1 = (const float*)d_in[10];
    const float* beta1  = (const float*)d_in[11];
    const float* Wl1    = (const float*)d_in[12];
    const float* bl1    = (const float*)d_in[13];
    const float* Wl2    = (const float*)d_in[14];
    const float* bl2    = (const float*)d_in[15];
    const float* Wc1    = (const float*)d_in[16];
    const float* bc1    = (const float*)d_in[17];
    const float* Wc2    = (const float*)d_in[18];
    const float* bc2    = (const float*)d_in[19];

    float* out = (float*)d_out;
    char* ws = (char*)d_ws;
    size_t off = 0;
    auto alloc = [&](size_t bytes) {
        void* p = ws + off;
        off += (bytes + 15) & ~(size_t)15;
        return p;
    };
    unsigned short* bufHb = (unsigned short*)alloc(sizeof(unsigned short) * (size_t)N_NODES * 128);
    unsigned short* bufAb = (unsigned short*)alloc(sizeof(unsigned short) * (size_t)N_NODES * 128);
    int2* edges = (int2*)alloc(sizeof(int2) * (size_t)N_EDGES);
    unsigned long long* degcnt = (unsigned long long*)alloc(sizeof(unsigned long long) * N_NODES);
    unsigned short* Wt0   = (unsigned short*)alloc(sizeof(unsigned short) * 128 * 128);
    unsigned short* Wt1   = (unsigned short*)alloc(sizeof(unsigned short) * 128 * 128);
    unsigned short* Wt2   = (unsigned short*)alloc(sizeof(unsigned short) * 128 * 128);
    unsigned short* Wt3   = (unsigned short*)alloc(sizeof(unsigned short) * 128 * 128);
    float* dinv   = (float*)alloc(sizeof(float) * N_NODES);
    int*   cnt    = (int*)alloc(sizeof(int) * N_NODES);
    int*   fillc  = (int*)alloc(sizeof(int) * N_NODES);
    float* stats0 = (float*)alloc(sizeof(float) * 256);
    float* stats1 = (float*)alloc(sizeof(float) * 256);
    float* bnp0   = (float*)alloc(sizeof(float) * 256);
    float* bnp1   = (float*)alloc(sizeof(float) * 256);
    float* gsum   = (float*)alloc(sizeof(float) * NGRAPH * 128);
    float* gcntf  = (float*)alloc(sizeof(float) * NGRAPH);
    int*   rowptr = (int*)alloc(sizeof(int) * (N_NODES + 1));
    int*   blockSum = (int*)alloc(sizeof(int) * SCAN_BLOCKS);

    // graph structure + weight prep
    init_kernel<<<(N_NODES + 255) / 256, 256, 0, stream>>>(degcnt, fillc, stats0,
                                                           stats1, gsum, gcntf);
    wprep_kernel<<<256, 256, 0, stream>>>(Wg0, Wg1, Wl1, Wl2, Wt0, Wt1, Wt2, Wt3);
    edge_degcnt_kernel<<<(N_EDGES + 255) / 256, 256, 0, stream>>>(ei, ea, degcnt);
    dinv_kernel<<<(N_NODES + 255) / 256, 256, 0, stream>>>(degcnt, cnt, dinv);
    scan1_kernel<<<SCAN_BLOCKS, 256, 0, stream>>>(cnt, blockSum);
    scan2_kernel<<<1, 512, 0, stream>>>(blockSum);
    scan3_kernel<<<SCAN_BLOCKS, 256, 0, stream>>>(cnt, blockSum, rowptr);
    fill_kernel<<<(N_EDGES + 255) / 256, 256, 0, stream>>>(ei, ea, dinv, rowptr, fillc,
                                                           edges);

    const int gemm_grid = (N_NODES + 127) / 128;   // 782
    const int agg_blocks = 2048;                   // 8192 waves
    const int agg_nwaves = agg_blocks * 4;
    // conv0: H0 = bf16(x) @ Wg0
    gemm_bf16_kernel<<<gemm_grid, 256, 0, stream>>>(x, 1, Wt0, bufHb, 0, nullptr, nullptr, 0);
    agg_relu_bf16_kernel<<<agg_blocks, 256, 0, stream>>>(bufHb, rowptr, edges,
                                                         dinv, bg0, bufAb, stats0, agg_nwaves);
    bn_finalize_kernel<<<1, 128, 0, stream>>>(stats0, gamma0, beta0, bnp0);
    // conv1: H1 = bn0(h) @ Wg1
    gemm_bf16_kernel<<<gemm_grid, 256, 0, stream>>>(bufAb, 0, Wt1, bufHb, 0, bnp0, nullptr, 0);
    agg_relu_bf16_kernel<<<agg_blocks, 256, 0, stream>>>(bufHb, rowptr, edges,
                                                         dinv, bg1, bufAb, stats1, agg_nwaves);
    bn_finalize_kernel<<<1, 128, 0, stream>>>(stats1, gamma1, beta1, bnp1);
    // lin1: relu(bn1(h) @ Wl1 + bl1) -> bf16 ; lin2: @ Wl2 + bl2 -> d_out fp32
    gemm_bf16_kernel<<<gemm_grid, 256, 0, stream>>>(bufAb, 0, Wt2, bufHb, 0, bnp1, bl1, 1);
    gemm_bf16_kernel<<<gemm_grid, 256, 0, stream>>>(bufHb, 0, Wt3, out, 1, nullptr, bl2, 0);
    // pooling + head
    pool_kernel<<<(N_NODES + 127) / 128, 256, 0, stream>>>(out, batch, gsum, gcntf);
    reps_kernel<<<(NGRAPH * 128 + 255) / 256, 256, 0, stream>>>(
        gsum, gcntf, out + (size_t)N_NODES * 128);
    logits_kernel<<<NGRAPH, 128, 0, stream>>>(out + (size_t)N_NODES * 128, Wc1, bc1, Wc2,
                                              bc2, out + (size_t)N_NODES * 128 + NGRAPH * 128);
}

// Round 3
// 680.196 us; speedup vs baseline: 1.0155x; 1.0155x over previous
//
#include <hip/hip_runtime.h>

#define N_NODES 100000
#define N_EDGES 1600000
#define DFEAT   128
#define NGRAPH  64
#define EPSV    1e-5f
#define SCAN_BLOCKS ((N_NODES + 255) / 256)   // 391
#define DEG_SCALE 268435456.0f                 // 2^28
#define DEG_MASK  ((1ULL << 42) - 1)

typedef float v4f  __attribute__((ext_vector_type(4)));
typedef short v8s  __attribute__((ext_vector_type(8)));   // 8 bf16 in 4 VGPRs
typedef unsigned short us4 __attribute__((ext_vector_type(4)));
typedef unsigned short us8 __attribute__((ext_vector_type(8)));

static __device__ __forceinline__ unsigned short f2bf(float f) {
    union { float f; unsigned int u; } v; v.f = f;
    unsigned int u = v.u;
    return (unsigned short)((u + 0x7FFFu + ((u >> 16) & 1u)) >> 16);   // RTNE
}
static __device__ __forceinline__ float bf2f(unsigned short b) {
    union { unsigned int u; float f; } v; v.u = ((unsigned int)b) << 16;
    return v.f;
}
static __device__ __forceinline__ int minI(int a, int b) { return a < b ? a : b; }

// ---------------------------------------------------------------------------
// init: degcnt=0 (packed), fillc=0, stats/pool buffers = 0
// ---------------------------------------------------------------------------
__global__ void init_kernel(unsigned long long* __restrict__ degcnt,
                            int* __restrict__ fillc, float* __restrict__ stats0,
                            float* __restrict__ stats1, float* __restrict__ gsum,
                            float* __restrict__ gcntf) {
    int i = blockIdx.x * 256 + threadIdx.x;
    if (i < N_NODES) { degcnt[i] = 0ULL; fillc[i] = 0; }
    if (i < 256)  { stats0[i] = 0.f; stats1[i] = 0.f; }
    if (i < NGRAPH * DFEAT) gsum[i] = 0.f;
    if (i < NGRAPH) gcntf[i] = 0.f;
}

// ---------------------------------------------------------------------------
// weight prep: Wt[n][k] = bf16(W[k][n]) for 4 weights (blockIdx>>6 selects)
// ---------------------------------------------------------------------------
__global__ __launch_bounds__(256) void wprep_kernel(
    const float* __restrict__ W0, const float* __restrict__ W1,
    const float* __restrict__ W2, const float* __restrict__ W3,
    unsigned short* __restrict__ T0, unsigned short* __restrict__ T1,
    unsigned short* __restrict__ T2, unsigned short* __restrict__ T3) {
    int which = blockIdx.x >> 6;
    int i = (blockIdx.x & 63) * 256 + threadIdx.x;   // 0..16383
    const float* W = which == 0 ? W0 : which == 1 ? W1 : which == 2 ? W2 : W3;
    unsigned short* T = which == 0 ? T0 : which == 1 ? T1 : which == 2 ? T2 : T3;
    int n = i >> 7, k = i & 127;
    T[n * 128 + k] = f2bf(W[k * 128 + n]);
}

// ---------------------------------------------------------------------------
// ONE packed u64 atomic per edge: cnt in [42:63], fixed-point sum(w) in [0:41]
// ---------------------------------------------------------------------------
__global__ void edge_degcnt_kernel(const int* __restrict__ ei, const float* __restrict__ ea,
                                   unsigned long long* __restrict__ degcnt) {
    int e = blockIdx.x * 256 + threadIdx.x;
    if (e >= N_EDGES) return;
    int d = ei[N_EDGES + e];
    float w = ea[2 * e + 1];           // w in [0,1)
    unsigned long long v = (1ULL << 42) | (unsigned long long)(w * DEG_SCALE);
    atomicAdd(&degcnt[d], v);
}

// unpack: cnt[i] (for scan) and dinv[i] = rsqrt(1 + sum_w)
__global__ void dinv_kernel(const unsigned long long* __restrict__ degcnt,
                            int* __restrict__ cnt, float* __restrict__ dinv) {
    int i = blockIdx.x * 256 + threadIdx.x;
    if (i >= N_NODES) return;
    unsigned long long u = degcnt[i];
    cnt[i] = (int)(u >> 42);
    float deg = 1.0f + (float)(u & DEG_MASK) * (1.0f / DEG_SCALE);
    dinv[i] = rsqrtf(deg);
}

// ---------------------------------------------------------------------------
// 3-phase device-wide exclusive scan of cnt -> rowptr
// ---------------------------------------------------------------------------
__global__ __launch_bounds__(256) void scan1_kernel(const int* __restrict__ cnt,
                                                    int* __restrict__ blockSum) {
    __shared__ int lds[256];
    int i = blockIdx.x * 256 + threadIdx.x;
    int t = threadIdx.x;
    lds[t] = (i < N_NODES) ? cnt[i] : 0;
    __syncthreads();
    for (int off = 128; off > 0; off >>= 1) {
        if (t < off) lds[t] += lds[t + off];
        __syncthreads();
    }
    if (t == 0) blockSum[blockIdx.x] = lds[0];
}

__global__ __launch_bounds__(512) void scan2_kernel(int* __restrict__ blockSum) {
    __shared__ int lds[512];
    int t = threadIdx.x;
    int v = (t < SCAN_BLOCKS) ? blockSum[t] : 0;
    lds[t] = v;
    __syncthreads();
    for (int off = 1; off < 512; off <<= 1) {
        int u = (t >= off) ? lds[t - off] : 0;
        __syncthreads();
        lds[t] += u;
        __syncthreads();
    }
    if (t < SCAN_BLOCKS) blockSum[t] = lds[t] - v;  // exclusive
}

__global__ __launch_bounds__(256) void scan3_kernel(const int* __restrict__ cnt,
                                                    const int* __restrict__ blockSum,
                                                    int* __restrict__ rowptr) {
    __shared__ int lds[256];
    int i = blockIdx.x * 256 + threadIdx.x;
    int t = threadIdx.x;
    int v = (i < N_NODES) ? cnt[i] : 0;
    lds[t] = v;
    __syncthreads();
    for (int off = 1; off < 256; off <<= 1) {
        int u = (t >= off) ? lds[t - off] : 0;
        __syncthreads();
        lds[t] += u;
        __syncthreads();
    }
    if (i < N_NODES) rowptr[i] = blockSum[blockIdx.x] + lds[t] - v;
    if (i == 0) rowptr[N_NODES] = N_EDGES;
}

// ---------------------------------------------------------------------------
// fill CSR: edges[pos] = {src, bitcast(val)} in ONE 8B store
// ---------------------------------------------------------------------------
__global__ void fill_kernel(const int* __restrict__ ei, const float* __restrict__ ea,
                            const float* __restrict__ dinv, const int* __restrict__ rowptr,
                            int* __restrict__ fillc, int2* __restrict__ edges) {
    int e = blockIdx.x * 256 + threadIdx.x;
    if (e >= N_EDGES) return;
    int s = ei[e], d = ei[N_EDGES + e];
    float w = ea[2 * e + 1];
    float nrm = dinv[s] * w * dinv[d];
    int pos = rowptr[d] + atomicAdd(&fillc[d], 1);
    edges[pos] = make_int2(s, __float_as_int(nrm));
}

// ---------------------------------------------------------------------------
// MFMA bf16 GEMM: Out[n x 128] = f(X) @ Wt^T (+bias)(+relu)
// ---------------------------------------------------------------------------
__global__ __launch_bounds__(256) void gemm_bf16_kernel(
    const void* __restrict__ Xv, int x_is_f32,
    const unsigned short* __restrict__ Wt,
    void* __restrict__ Outv, int out_is_f32,
    const float* __restrict__ bnp, const float* __restrict__ bias, int do_relu) {
    __shared__ unsigned short Xs[128][136];
    __shared__ unsigned short Ws[128][136];
    const int tid = threadIdx.x;
    const int rb = blockIdx.x * 128;

#pragma unroll
    for (int it = 0; it < 8; ++it) {
        int flat = it * 2048 + tid * 8;
        int n = flat >> 7, k = flat & 127;
        *(us8*)&Ws[n][k] = *(const us8*)&Wt[n * 128 + k];
    }
    if (x_is_f32) {
        const float* X = (const float*)Xv;
#pragma unroll
        for (int it = 0; it < 16; ++it) {
            int flat = it * 1024 + tid * 4;
            int r = flat >> 7, k = flat & 127;
            float4 v = make_float4(0.f, 0.f, 0.f, 0.f);
            if (rb + r < N_NODES) v = *(const float4*)&X[(size_t)(rb + r) * 128 + k];
            if (bnp) {
                v.x = v.x * bnp[k]     + bnp[128 + k];
                v.y = v.y * bnp[k + 1] + bnp[129 + k];
                v.z = v.z * bnp[k + 2] + bnp[130 + k];
                v.w = v.w * bnp[k + 3] + bnp[131 + k];
            }
            us4 o; o.x = f2bf(v.x); o.y = f2bf(v.y); o.z = f2bf(v.z); o.w = f2bf(v.w);
            *(us4*)&Xs[r][k] = o;
        }
    } else {
        const unsigned short* X = (const unsigned short*)Xv;
#pragma unroll
        for (int it = 0; it < 8; ++it) {
            int flat = it * 2048 + tid * 8;
            int r = flat >> 7, k = flat & 127;
            us8 v = {0, 0, 0, 0, 0, 0, 0, 0};
            if (rb + r < N_NODES) v = *(const us8*)&X[(size_t)(rb + r) * 128 + k];
            if (bnp) {
#pragma unroll
                for (int j = 0; j < 8; ++j)
                    v[j] = f2bf(bf2f(v[j]) * bnp[k + j] + bnp[128 + k + j]);
            }
            *(us8*)&Xs[r][k] = v;
        }
    }
    __syncthreads();

    const int wv = tid >> 6, lane = tid & 63;
    const int q = lane >> 4, c16 = lane & 15;
    v4f acc[2][8];
#pragma unroll
    for (int i = 0; i < 2; ++i)
#pragma unroll
        for (int j = 0; j < 8; ++j) acc[i][j] = (v4f){0.f, 0.f, 0.f, 0.f};

#pragma unroll
    for (int ks = 0; ks < 4; ++ks) {
        v8s a0 = *(const v8s*)&Xs[wv * 32 + c16][ks * 32 + q * 8];
        v8s a1 = *(const v8s*)&Xs[wv * 32 + 16 + c16][ks * 32 + q * 8];
#pragma unroll
        for (int nt = 0; nt < 8; ++nt) {
            v8s b = *(const v8s*)&Ws[nt * 16 + c16][ks * 32 + q * 8];
            acc[0][nt] = __builtin_amdgcn_mfma_f32_16x16x32_bf16(a0, b, acc[0][nt], 0, 0, 0);
            acc[1][nt] = __builtin_amdgcn_mfma_f32_16x16x32_bf16(a1, b, acc[1][nt], 0, 0, 0);
        }
    }

#pragma unroll
    for (int mt = 0; mt < 2; ++mt) {
#pragma unroll
        for (int nt = 0; nt < 8; ++nt) {
            int col = nt * 16 + c16;
            float bcol = bias ? bias[col] : 0.f;
#pragma unroll
            for (int r = 0; r < 4; ++r) {
                int row = rb + wv * 32 + mt * 16 + q * 4 + r;
                if (row >= N_NODES) continue;
                float o = acc[mt][nt][r] + bcol;
                if (do_relu) o = fmaxf(o, 0.f);
                if (out_is_f32) ((float*)Outv)[(size_t)row * 128 + col] = o;
                else ((unsigned short*)Outv)[(size_t)row * 128 + col] = f2bf(o);
            }
        }
    }
}

// ---------------------------------------------------------------------------
// aggregation (bf16 gather) + self term + bias + relu + BN stats (fp32)
// R3: TWO-STRAND row pipeline. Each wave processes rows (i, i+nwaves)
// concurrently in straight-line code: both strands' edge records (scalar
// path) and gathers are in flight together, halving serial latency chains
// per row. Tail slots clamp to a valid edge (L1-hit) with weight 0.
// ---------------------------------------------------------------------------
__global__ __launch_bounds__(256) void agg_relu_bf16_kernel(
    const unsigned short* __restrict__ H, const int* __restrict__ rowptr,
    const int2* __restrict__ edges,
    const float* __restrict__ dinv, const float* __restrict__ bias,
    unsigned short* __restrict__ outb, float* __restrict__ stats, int nwaves) {
    __shared__ float red[1024];
    const int tid = threadIdx.x;
    const int wv = tid >> 6;
    const int lane = tid & 63;
    const float bx = bias[2 * lane], by = bias[2 * lane + 1];
    const unsigned int* __restrict__ H4 = (const unsigned int*)H;   // 64 uints/row
    unsigned int* __restrict__ O4 = (unsigned int*)outb;
    float s0 = 0.f, q0 = 0.f, s1 = 0.f, q1 = 0.f;

    for (int i = blockIdx.x * 4 + wv; i < N_NODES; i += 2 * nwaves) {
        const int iA = i;
        const int iB = i + nwaves;
        const int hasB = iB < N_NODES;
        const int iBs = hasB ? iB : iA;

        int begA = __builtin_amdgcn_readfirstlane(rowptr[iA]);
        int endA = __builtin_amdgcn_readfirstlane(rowptr[iA + 1]);
        int begB = __builtin_amdgcn_readfirstlane(rowptr[iBs]);
        int endB = __builtin_amdgcn_readfirstlane(rowptr[iBs + 1]);
        // self rows + dinv hoisted: in flight during the whole edge loop
        float diA = dinv[iA];
        float diB = dinv[iBs];
        unsigned int hsA = H4[(size_t)iA * 64 + lane];
        unsigned int hsB = H4[(size_t)iBs * 64 + lane];

        const int nA = endA - begA;
        const int nB = hasB ? (endB - begB) : 0;
        const int lA = nA > 0 ? endA - 1 : 0;
        const int lB = nB > 0 ? endB - 1 : 0;
        const int nmax = nA > nB ? nA : nB;

        float axA0 = 0.f, ayA0 = 0.f, axA1 = 0.f, ayA1 = 0.f;
        float axB0 = 0.f, ayB0 = 0.f, axB1 = 0.f, ayB1 = 0.f;

        for (int c = 0; c < nmax; c += 8) {
            const int jA = begA + c, jB = begB + c;
            // ---- edge records, both strands (scalar/uniform loads) ----
            int2 a0 = edges[minI(jA + 0, lA)];
            int2 a1 = edges[minI(jA + 1, lA)];
            int2 a2 = edges[minI(jA + 2, lA)];
            int2 a3 = edges[minI(jA + 3, lA)];
            int2 a4 = edges[minI(jA + 4, lA)];
            int2 a5 = edges[minI(jA + 5, lA)];
            int2 a6 = edges[minI(jA + 6, lA)];
            int2 a7 = edges[minI(jA + 7, lA)];
            int2 b0 = edges[minI(jB + 0, lB)];
            int2 b1 = edges[minI(jB + 1, lB)];
            int2 b2 = edges[minI(jB + 2, lB)];
            int2 b3 = edges[minI(jB + 3, lB)];
            int2 b4 = edges[minI(jB + 4, lB)];
            int2 b5 = edges[minI(jB + 5, lB)];
            int2 b6 = edges[minI(jB + 6, lB)];
            int2 b7 = edges[minI(jB + 7, lB)];
            // ---- gathers, both strands (16 in flight) ----
            unsigned int hA0 = H4[(size_t)(unsigned)a0.x * 64 + lane];
            unsigned int hA1 = H4[(size_t)(unsigned)a1.x * 64 + lane];
            unsigned int hA2 = H4[(size_t)(unsigned)a2.x * 64 + lane];
            unsigned int hA3 = H4[(size_t)(unsigned)a3.x * 64 + lane];
            unsigned int hA4 = H4[(size_t)(unsigned)a4.x * 64 + lane];
            unsigned int hA5 = H4[(size_t)(unsigned)a5.x * 64 + lane];
            unsigned int hA6 = H4[(size_t)(unsigned)a6.x * 64 + lane];
            unsigned int hA7 = H4[(size_t)(unsigned)a7.x * 64 + lane];
            unsigned int hB0 = H4[(size_t)(unsigned)b0.x * 64 + lane];
            unsigned int hB1 = H4[(size_t)(unsigned)b1.x * 64 + lane];
            unsigned int hB2 = H4[(size_t)(unsigned)b2.x * 64 + lane];
            unsigned int hB3 = H4[(size_t)(unsigned)b3.x * 64 + lane];
            unsigned int hB4 = H4[(size_t)(unsigned)b4.x * 64 + lane];
            unsigned int hB5 = H4[(size_t)(unsigned)b5.x * 64 + lane];
            unsigned int hB6 = H4[(size_t)(unsigned)b6.x * 64 + lane];
            unsigned int hB7 = H4[(size_t)(unsigned)b7.x * 64 + lane];
            // ---- weights (masked tails -> 0) ----
            float wA0 = (c + 0 < nA) ? __int_as_float(a0.y) : 0.f;
            float wA1 = (c + 1 < nA) ? __int_as_float(a1.y) : 0.f;
            float wA2 = (c + 2 < nA) ? __int_as_float(a2.y) : 0.f;
            float wA3 = (c + 3 < nA) ? __int_as_float(a3.y) : 0.f;
            float wA4 = (c + 4 < nA) ? __int_as_float(a4.y) : 0.f;
            float wA5 = (c + 5 < nA) ? __int_as_float(a5.y) : 0.f;
            float wA6 = (c + 6 < nA) ? __int_as_float(a6.y) : 0.f;
            float wA7 = (c + 7 < nA) ? __int_as_float(a7.y) : 0.f;
            float wB0 = (c + 0 < nB) ? __int_as_float(b0.y) : 0.f;
            float wB1 = (c + 1 < nB) ? __int_as_float(b1.y) : 0.f;
            float wB2 = (c + 2 < nB) ? __int_as_float(b2.y) : 0.f;
            float wB3 = (c + 3 < nB) ? __int_as_float(b3.y) : 0.f;
            float wB4 = (c + 4 < nB) ? __int_as_float(b4.y) : 0.f;
            float wB5 = (c + 5 < nB) ? __int_as_float(b5.y) : 0.f;
            float wB6 = (c + 6 < nB) ? __int_as_float(b6.y) : 0.f;
            float wB7 = (c + 7 < nB) ? __int_as_float(b7.y) : 0.f;
            // ---- FMAs ----
            axA0 = fmaf(wA0, bf2f((unsigned short)hA0), axA0);
            ayA0 = fmaf(wA0, bf2f((unsigned short)(hA0 >> 16)), ayA0);
            axA1 = fmaf(wA1, bf2f((unsigned short)hA1), axA1);
            ayA1 = fmaf(wA1, bf2f((unsigned short)(hA1 >> 16)), ayA1);
            axA0 = fmaf(wA2, bf2f((unsigned short)hA2), axA0);
            ayA0 = fmaf(wA2, bf2f((unsigned short)(hA2 >> 16)), ayA0);
            axA1 = fmaf(wA3, bf2f((unsigned short)hA3), axA1);
            ayA1 = fmaf(wA3, bf2f((unsigned short)(hA3 >> 16)), ayA1);
            axA0 = fmaf(wA4, bf2f((unsigned short)hA4), axA0);
            ayA0 = fmaf(wA4, bf2f((unsigned short)(hA4 >> 16)), ayA0);
            axA1 = fmaf(wA5, bf2f((unsigned short)hA5), axA1);
            ayA1 = fmaf(wA5, bf2f((unsigned short)(hA5 >> 16)), ayA1);
            axA0 = fmaf(wA6, bf2f((unsigned short)hA6), axA0);
            ayA0 = fmaf(wA6, bf2f((unsigned short)(hA6 >> 16)), ayA0);
            axA1 = fmaf(wA7, bf2f((unsigned short)hA7), axA1);
            ayA1 = fmaf(wA7, bf2f((unsigned short)(hA7 >> 16)), ayA1);
            axB0 = fmaf(wB0, bf2f((unsigned short)hB0), axB0);
            ayB0 = fmaf(wB0, bf2f((unsigned short)(hB0 >> 16)), ayB0);
            axB1 = fmaf(wB1, bf2f((unsigned short)hB1), axB1);
            ayB1 = fmaf(wB1, bf2f((unsigned short)(hB1 >> 16)), ayB1);
            axB0 = fmaf(wB2, bf2f((unsigned short)hB2), axB0);
            ayB0 = fmaf(wB2, bf2f((unsigned short)(hB2 >> 16)), ayB0);
            axB1 = fmaf(wB3, bf2f((unsigned short)hB3), axB1);
            ayB1 = fmaf(wB3, bf2f((unsigned short)(hB3 >> 16)), ayB1);
            axB0 = fmaf(wB4, bf2f((unsigned short)hB4), axB0);
            ayB0 = fmaf(wB4, bf2f((unsigned short)(hB4 >> 16)), ayB0);
            axB1 = fmaf(wB5, bf2f((unsigned short)hB5), axB1);
            ayB1 = fmaf(wB5, bf2f((unsigned short)(hB5 >> 16)), ayB1);
            axB0 = fmaf(wB6, bf2f((unsigned short)hB6), axB0);
            ayB0 = fmaf(wB6, bf2f((unsigned short)(hB6 >> 16)), ayB0);
            axB1 = fmaf(wB7, bf2f((unsigned short)hB7), axB1);
            ayB1 = fmaf(wB7, bf2f((unsigned short)(hB7 >> 16)), ayB1);
        }

        // ---- finalize strand A ----
        {
            float dd = diA * diA;
            float ax = axA0 + axA1;
            float ay = ayA0 + ayA1;
            ax = fmaf(dd, bf2f((unsigned short)hsA), ax) + bx;
            ay = fmaf(dd, bf2f((unsigned short)(hsA >> 16)), ay) + by;
            ax = fmaxf(ax, 0.f);
            ay = fmaxf(ay, 0.f);
            O4[(size_t)iA * 64 + lane] =
                (unsigned int)f2bf(ax) | ((unsigned int)f2bf(ay) << 16);
            s0 += ax; q0 += ax * ax; s1 += ay; q1 += ay * ay;
        }
        // ---- finalize strand B ----
        if (hasB) {
            float dd = diB * diB;
            float ax = axB0 + axB1;
            float ay = ayB0 + ayB1;
            ax = fmaf(dd, bf2f((unsigned short)hsB), ax) + bx;
            ay = fmaf(dd, bf2f((unsigned short)(hsB >> 16)), ay) + by;
            ax = fmaxf(ax, 0.f);
            ay = fmaxf(ay, 0.f);
            O4[(size_t)iB * 64 + lane] =
                (unsigned int)f2bf(ax) | ((unsigned int)f2bf(ay) << 16);
            s0 += ax; q0 += ax * ax; s1 += ay; q1 += ay * ay;
        }
    }

    red[wv * 128 + 2 * lane]           = s0;
    red[wv * 128 + 2 * lane + 1]       = s1;
    red[512 + wv * 128 + 2 * lane]     = q0;
    red[512 + wv * 128 + 2 * lane + 1] = q1;
    __syncthreads();
    if (tid < 128) {
        float ts = red[tid] + red[128 + tid] + red[256 + tid] + red[384 + tid];
        float tq = red[512 + tid] + red[640 + tid] + red[768 + tid] + red[896 + tid];
        atomicAdd(&stats[tid], ts);
        atomicAdd(&stats[128 + tid], tq);
    }
}

// stats -> per-feature scale/shift
__global__ void bn_finalize_kernel(const float* __restrict__ stats,
                                   const float* __restrict__ gamma,
                                   const float* __restrict__ beta,
                                   float* __restrict__ bnp) {
    int f = threadIdx.x;
    float mean = stats[f] / (float)N_NODES;
    float var = stats[128 + f] / (float)N_NODES - mean * mean;
    float sc = gamma[f] * rsqrtf(var + EPSV);
    bnp[f] = sc;
    bnp[128 + f] = beta[f] - mean * sc;
}

// ---------------------------------------------------------------------------
// pooling: batch sorted; 128 rows/block, 256 threads = (feature, row-parity),
// run-length accumulate per thread, flush on graph change. ~12 waves/CU.
// ---------------------------------------------------------------------------
__global__ __launch_bounds__(256) void pool_kernel(const float* __restrict__ h,
                                                   const int* __restrict__ batch,
                                                   float* __restrict__ gsum,
                                                   float* __restrict__ gcntf) {
    const int f = threadIdx.x & 127;
    const int half = threadIdx.x >> 7;          // 0/1: even/odd rows
    const int base = blockIdx.x * 128;
    int r = base + half;
    const int end = (base + 128 < N_NODES) ? base + 128 : N_NODES;
    if (r >= end) return;
    int cur = batch[r];
    float sum = 0.f, cnt = 0.f;
    for (; r < end; r += 2) {
        int g = batch[r];
        if (g != cur) {
            atomicAdd(&gsum[cur * 128 + f], sum);
            if (f == 0) atomicAdd(&gcntf[cur], cnt);
            sum = 0.f; cnt = 0.f; cur = g;
        }
        sum += h[(size_t)r * 128 + f];
        cnt += 1.f;
    }
    atomicAdd(&gsum[cur * 128 + f], sum);
    if (f == 0) atomicAdd(&gcntf[cur], cnt);
}

__global__ void reps_kernel(const float* __restrict__ gsum,
                            const float* __restrict__ gcntf,
                            float* __restrict__ out_reps) {
    int i = blockIdx.x * 256 + threadIdx.x;
    if (i < NGRAPH * 128) {
        int g = i >> 7;
        out_reps[i] = gsum[i] / fmaxf(gcntf[g], 1.0f);
    }
}

__global__ __launch_bounds__(128) void logits_kernel(
    const float* __restrict__ reps, const float* __restrict__ Wc1,
    const float* __restrict__ bc1, const float* __restrict__ Wc2,
    const float* __restrict__ bc2, float* __restrict__ out_logits) {
    __shared__ float repS[128];
    __shared__ float tmp[128];
    int g = blockIdx.x, t = threadIdx.x;
    repS[t] = reps[(size_t)g * 128 + t];
    __syncthreads();
    float acc = bc1[t];
    for (int k = 0; k < 128; ++k) acc = fmaf(repS[k], Wc1[k * 128 + t], acc);
    tmp[t] = fmaxf(acc, 0.f);
    __syncthreads();
    if (t < 2) {
        float a = bc2[t];
        for (int k = 0; k < 128; ++k) a = fmaf(tmp[k], Wc2[k * 2 + t], a);
        out_logits[g * 2 + t] = a;
    }
}

// ---------------------------------------------------------------------------
extern "C" void kernel_launch(void* const* d_in, const int* in_sizes, int n_in,
                              void* d_out, int out_size, void* d_ws, size_t ws_size,
                              hipStream_t stream) {
    const float* x      = (const float*)d_in[0];
    const int*   ei     = (const int*)d_in[1];
    const float* ea     = (const float*)d_in[2];
    const int*   batch  = (const int*)d_in[3];
    const float* Wg0    = (const float*)d_in[4];
    const float* bg0    = (const float*)d_in[5];
    const float* gamma0 = (const float*)d_in[6];
    const float* beta0  = (const float*)d_in[7];
    const float* Wg1    = (const float*)d_in[8];
    const float* bg1    = (const float*)d_in[9];
    const float* gamma1 = (const float*)d_in[10];
    const float* beta1  = (const float*)d_in[11];
    const float* Wl1    = (const float*)d_in[12];
    const float* bl1    = (const float*)d_in[13];
    const float* Wl2    = (const float*)d_in[14];
    const float* bl2    = (const float*)d_in[15];
    const float* Wc1    = (const float*)d_in[16];
    const float* bc1    = (const float*)d_in[17];
    const float* Wc2    = (const float*)d_in[18];
    const float* bc2    = (const float*)d_in[19];

    float* out = (float*)d_out;
    char* ws = (char*)d_ws;
    size_t off = 0;
    auto alloc = [&](size_t bytes) {
        void* p = ws + off;
        off += (bytes + 15) & ~(size_t)15;
        return p;
    };
    unsigned short* bufHb = (unsigned short*)alloc(sizeof(unsigned short) * (size_t)N_NODES * 128);
    unsigned short* bufAb = (unsigned short*)alloc(sizeof(unsigned short) * (size_t)N_NODES * 128);
    int2* edges = (int2*)alloc(sizeof(int2) * (size_t)N_EDGES);
    unsigned long long* degcnt = (unsigned long long*)alloc(sizeof(unsigned long long) * N_NODES);
    unsigned short* Wt0   = (unsigned short*)alloc(sizeof(unsigned short) * 128 * 128);
    unsigned short* Wt1   = (unsigned short*)alloc(sizeof(unsigned short) * 128 * 128);
    unsigned short* Wt2   = (unsigned short*)alloc(sizeof(unsigned short) * 128 * 128);
    unsigned short* Wt3   = (unsigned short*)alloc(sizeof(unsigned short) * 128 * 128);
    float* dinv   = (float*)alloc(sizeof(float) * N_NODES);
    int*   cnt    = (int*)alloc(sizeof(int) * N_NODES);
    int*   fillc  = (int*)alloc(sizeof(int) * N_NODES);
    float* stats0 = (float*)alloc(sizeof(float) * 256);
    float* stats1 = (float*)alloc(sizeof(float) * 256);
    float* bnp0   = (float*)alloc(sizeof(float) * 256);
    float* bnp1   = (float*)alloc(sizeof(float) * 256);
    float* gsum   = (float*)alloc(sizeof(float) * NGRAPH * 128);
    float* gcntf  = (float*)alloc(sizeof(float) * NGRAPH);
    int*   rowptr = (int*)alloc(sizeof(int) * (N_NODES + 1));
    int*   blockSum = (int*)alloc(sizeof(int) * SCAN_BLOCKS);

    // graph structure + weight prep
    init_kernel<<<(N_NODES + 255) / 256, 256, 0, stream>>>(degcnt, fillc, stats0,
                                                           stats1, gsum, gcntf);
    wprep_kernel<<<256, 256, 0, stream>>>(Wg0, Wg1, Wl1, Wl2, Wt0, Wt1, Wt2, Wt3);
    edge_degcnt_kernel<<<(N_EDGES + 255) / 256, 256, 0, stream>>>(ei, ea, degcnt);
    dinv_kernel<<<(N_NODES + 255) / 256, 256, 0, stream>>>(degcnt, cnt, dinv);
    scan1_kernel<<<SCAN_BLOCKS, 256, 0, stream>>>(cnt, blockSum);
    scan2_kernel<<<1, 512, 0, stream>>>(blockSum);
    scan3_kernel<<<SCAN_BLOCKS, 256, 0, stream>>>(cnt, blockSum, rowptr);
    fill_kernel<<<(N_EDGES + 255) / 256, 256, 0, stream>>>(ei, ea, dinv, rowptr, fillc,
                                                           edges);

    const int gemm_grid = (N_NODES + 127) / 128;   // 782
    const int agg_blocks = 2048;                   // 8192 waves
    const int agg_nwaves = agg_blocks * 4;
    // conv0: H0 = bf16(x) @ Wg0
    gemm_bf16_kernel<<<gemm_grid, 256, 0, stream>>>(x, 1, Wt0, bufHb, 0, nullptr, nullptr, 0);
    agg_relu_bf16_kernel<<<agg_blocks, 256, 0, stream>>>(bufHb, rowptr, edges,
                                                         dinv, bg0, bufAb, stats0, agg_nwaves);
    bn_finalize_kernel<<<1, 128, 0, stream>>>(stats0, gamma0, beta0, bnp0);
    // conv1: H1 = bn0(h) @ Wg1
    gemm_bf16_kernel<<<gemm_grid, 256, 0, stream>>>(bufAb, 0, Wt1, bufHb, 0, bnp0, nullptr, 0);
    agg_relu_bf16_kernel<<<agg_blocks, 256, 0, stream>>>(bufHb, rowptr, edges,
                                                         dinv, bg1, bufAb, stats1, agg_nwaves);
    bn_finalize_kernel<<<1, 128, 0, stream>>>(stats1, gamma1, beta1, bnp1);
    // lin1: relu(bn1(h) @ Wl1 + bl1) -> bf16 ; lin2: @ Wl2 + bl2 -> d_out fp32
    gemm_bf16_kernel<<<gemm_grid, 256, 0, stream>>>(bufAb, 0, Wt2, bufHb, 0, bnp1, bl1, 1);
    gemm_bf16_kernel<<<gemm_grid, 256, 0, stream>>>(bufHb, 0, Wt3, out, 1, nullptr, bl2, 0);
    // pooling + head
    pool_kernel<<<(N_NODES + 127) / 128, 256, 0, stream>>>(out, batch, gsum, gcntf);
    reps_kernel<<<(NGRAPH * 128 + 255) / 256, 256, 0, stream>>>(
        gsum, gcntf, out + (size_t)N_NODES * 128);
    logits_kernel<<<NGRAPH, 128, 0, stream>>>(out + (size_t)N_NODES * 128, Wc1, bc1, Wc2,
                                              bc2, out + (size_t)N_NODES * 128 + NGRAPH * 128);
}